// Round 1
// baseline (286.847 us; speedup 1.0000x reference)
//
#include <hip/hip_runtime.h>
#include <hip/hip_bf16.h>
#include <stdint.h>
#include <stddef.h>

// Problem: B=4096, E=16, D=512, H=2048
// out[b,h] = sum_e relu( x_b . W[e,h,:] - c_e . W[e,h,:] + b[e,h] )
// GEMM view: M=4096, N=E*H (expert-looped), K=512. 137.4 GFLOP.
// R6: 128x64 tile, 2-expert pass, XOR-swizzled LDS (0 bank conflicts),
//     double-buffer + __syncthreads  -> 165 us = 833 TF = m97-structure
//     ceiling (MfmaUtil 37.8%). The syncthreads forces vmcnt(0) drain.
// R7: T4 counted-vmcnt graft: 4 LDS buffers, raw s_barrier + asm
//     s_waitcnt vmcnt(8) -> 2 stages (8 global_load_lds) stay in flight
//     across every barrier. LDS 68 KB -> 2 blocks/CU, grid 1024 = 2 clean
//     rounds. + T5 setprio around MFMA cluster.
//     prep: 2 W-rows/wave (half-wave reduce), 16 floats/thread X pass.

#define B_DIM 4096
#define E_DIM 16
#define D_DIM 512
#define H_DIM 2048

typedef short bf16x8 __attribute__((ext_vector_type(8)));
typedef float f32x4 __attribute__((ext_vector_type(4)));

__device__ __forceinline__ short f2bf(float f) {
  __hip_bfloat16 h = __float2bfloat16(f);  // RNE
  return *reinterpret_cast<short*>(&h);
}

__device__ __forceinline__ bf16x8 cvt8(float4 a, float4 b) {
  bf16x8 v;
  v[0] = f2bf(a.x); v[1] = f2bf(a.y); v[2] = f2bf(a.z); v[3] = f2bf(a.w);
  v[4] = f2bf(b.x); v[5] = f2bf(b.y); v[6] = f2bf(b.z); v[7] = f2bf(b.w);
  return v;
}

__device__ __forceinline__ float dot4(float4 a, float4 b) {
  return a.x * b.x + a.y * b.y + a.z * b.z + a.w * b.w;
}

// async global->LDS, 16 bytes per lane. LDS dest must be uniform_base + lane*16.
__device__ __forceinline__ void async_copy16(const void* gptr, void* lptr) {
  __builtin_amdgcn_global_load_lds(
      (const __attribute__((address_space(1))) void*)gptr,
      (__attribute__((address_space(3))) void*)lptr,
      16, 0, 0);
}

// ---------------------------------------------------------------------------
// Merged prepass.
// Blocks [0,4096): each wave handles TWO W rows (lanes 0-31 -> row 2w,
//   lanes 32-63 -> row 2w+1; rows of a pair never straddle an expert since
//   H=2048 is even). Per lane: 16 W floats (4x float4 in flight) -> bf16,
//   plus partial dot(c_e, row) reduced within the 32-lane half.
// Blocks [4096,4608): convert x, 16 floats/thread.
// ---------------------------------------------------------------------------
__global__ __launch_bounds__(256) void prep(
    const float* __restrict__ W, const float* __restrict__ C,
    const float* __restrict__ bias, const float* __restrict__ X,
    __hip_bfloat16* __restrict__ Wb, float* __restrict__ bias2,
    __hip_bfloat16* __restrict__ Xb) {
  if (blockIdx.x < 4096) {
    const int wid = (blockIdx.x * 256 + threadIdx.x) >> 6;  // wave id 0..16383
    const int lane = threadIdx.x & 63;
    const int half = lane >> 5;
    const int l = lane & 31;
    const int gw = wid * 2 + half;  // W row id 0..32767
    const int e = gw >> 11;         // / H_DIM

    const float* wr = W + (size_t)gw * D_DIM + l * 16;
    const float* cr = C + (size_t)e * D_DIM + l * 16;
    float4 w0 = *(const float4*)(wr);
    float4 w1 = *(const float4*)(wr + 4);
    float4 w2 = *(const float4*)(wr + 8);
    float4 w3 = *(const float4*)(wr + 12);
    float4 c0 = *(const float4*)(cr);
    float4 c1 = *(const float4*)(cr + 4);
    float4 c2 = *(const float4*)(cr + 8);
    float4 c3 = *(const float4*)(cr + 12);

    __hip_bfloat16* wb = Wb + (size_t)gw * D_DIM + l * 16;
    *(bf16x8*)(wb) = cvt8(w0, w1);
    *(bf16x8*)(wb + 8) = cvt8(w2, w3);

    float dot = dot4(w0, c0) + dot4(w1, c1) + dot4(w2, c2) + dot4(w3, c3);
#pragma unroll
    for (int off = 16; off > 0; off >>= 1) dot += __shfl_down(dot, off, 32);
    if (l == 0) bias2[gw] = bias[gw] - dot;
  } else {
    const size_t i = ((size_t)(blockIdx.x - 4096) * 256 + threadIdx.x) * 16;
    float4 a0 = *(const float4*)(X + i);
    float4 a1 = *(const float4*)(X + i + 4);
    float4 a2 = *(const float4*)(X + i + 8);
    float4 a3 = *(const float4*)(X + i + 12);
    *(bf16x8*)(Xb + i) = cvt8(a0, a1);
    *(bf16x8*)(Xb + i + 8) = cvt8(a2, a3);
  }
}

// ---------------------------------------------------------------------------
// Main kernel R7: tile m=128 x n=64, 4 waves (2m x 2n), wave = 64m x 32n per
// expert, 2 experts per K-pass (shared A fragments). XOR bank swizzle as R6:
//   chunk slot (row, q) stores global k-chunk q ^ ((row>>1)&3)  (conflict-free,
//   SQ_LDS_BANK_CONFLICT == 0 measured).
// Pipeline (T4): 4 LDS buffers; stage(t+3) issued in phase t; end of phase t
// waits s_waitcnt vmcnt(8) (drains own S(t+1), leaves S(t+2),S(t+3) in
// flight) then raw s_barrier. Per-wave FIFO drain before the barrier
// guarantees the full tile is written for all waves. Buffer (t+3)&3 being
// overwritten was last read in phase t-1, whose end barrier precedes this
// issue. LDS 68 KB => 2 blocks/CU (8 waves/CU), grid 1024 = 2 exact rounds.
// ---------------------------------------------------------------------------
__global__ __launch_bounds__(256, 2) void moe_gemm(
    const __hip_bfloat16* __restrict__ Xb,   // [4096, 512]
    const __hip_bfloat16* __restrict__ Wb,   // [16, 2048, 512]
    const float* __restrict__ bias2,         // [16, 2048]
    float* __restrict__ out) {               // [4096, 2048]
  __shared__ __align__(16) __hip_bfloat16 As[4][128 * 32];     // 32 KB
  __shared__ __align__(16) __hip_bfloat16 Bs[4][2][64 * 32];   // 32 KB
  __shared__ __align__(16) float biasS[E_DIM * 64];            // 4 KB

  const int tid = threadIdx.x;
  const int lane = tid & 63;
  const int wave = tid >> 6;
  const int hi = blockIdx.x & 31;
  const int mi = blockIdx.x >> 5;
  const int m0 = mi * 128;
  const int h0 = hi * 64;

  const int wm = (wave & 1) * 64;
  const int wn = (wave >> 1) * 32;
  const int lm = lane & 15;
  const int q = lane >> 4;

  // ---- staging: thread t handles A chunks t,t+256 and B0/B1 chunk t.
  // Swizzled source: fetch global k-chunk (t&3) ^ ((row>>1)&3).
  const int r = tid >> 2;                       // rows 0..63
  const int fr = (r >> 1) & 3;                  // same for row r and r+64
  const int col = (((tid & 3) ^ fr)) << 3;      // swizzled k elem offset
  const size_t aOff0 = (size_t)(m0 + r) * D_DIM + col;
  const size_t aOff1 = (size_t)(m0 + r + 64) * D_DIM + col;
  const size_t bOff = (size_t)(h0 + r) * D_DIM + col;  // B rows 0..63
  const int ldA0 = tid * 8;
  const int ldA1 = (tid + 256) * 8;
  const int ldB = tid * 8;

  // ---- read-side element offsets: (row R, k-chunk q) at slot q^((R>>1)&3)
  int offA[4], offB[2];
#pragma unroll
  for (int i = 0; i < 4; ++i) {
    const int R = wm + i * 16 + lm;
    offA[i] = R * 32 + ((q ^ ((R >> 1) & 3)) << 3);
  }
#pragma unroll
  for (int j = 0; j < 2; ++j) {
    const int R = wn + j * 16 + lm;
    offB[j] = R * 32 + ((q ^ ((R >> 1) & 3)) << 3);
  }

  f32x4 sum[4][2], acc0[4][2], acc1[4][2];
#pragma unroll
  for (int i = 0; i < 4; ++i)
#pragma unroll
    for (int j = 0; j < 2; ++j) {
      sum[i][j] = (f32x4){0.f, 0.f, 0.f, 0.f};
      acc0[i][j] = (f32x4){0.f, 0.f, 0.f, 0.f};
      acc1[i][j] = (f32x4){0.f, 0.f, 0.f, 0.f};
    }

  // phase t: pair = t>>4, ks = t&15. stage(tt) fills buffer tt&3.
#define STAGE(buf, tt)                                                      \
  {                                                                         \
    const int kk = ((tt) & 15) << 5;                                        \
    const __hip_bfloat16* Bb = Wb + ((size_t)((tt) >> 4) << 21) + bOff + kk;\
    async_copy16(Xb + aOff0 + kk, &As[buf][ldA0]);                          \
    async_copy16(Xb + aOff1 + kk, &As[buf][ldA1]);                          \
    async_copy16(Bb, &Bs[buf][0][ldB]);                                     \
    async_copy16(Bb + ((size_t)1 << 20), &Bs[buf][1][ldB]);                 \
  }

  // prologue: 3 stages in flight + bias preload. (The bias2 register loads
  // force a conservative vmcnt drain here once; the loop re-fills depth.)
  STAGE(0, 0);
  STAGE(1, 1);
  STAGE(2, 2);
  for (int idx = tid; idx < E_DIM * 64; idx += 256) {
    biasS[idx] = bias2[((idx >> 6) << 11) + h0 + (idx & 63)];
  }
  asm volatile("s_waitcnt vmcnt(8) lgkmcnt(0)" ::: "memory");
  __builtin_amdgcn_s_barrier();
  __builtin_amdgcn_sched_barrier(0);

  for (int t = 0; t < 128; ++t) {
    const int cur = t & 3;
    if (t + 3 < 128) STAGE((t + 3) & 3, t + 3);  // keep 2-3 stages in flight

    bf16x8 af[4];
#pragma unroll
    for (int i = 0; i < 4; ++i) af[i] = *(const bf16x8*)&As[cur][offA[i]];

    __builtin_amdgcn_s_setprio(1);
#pragma unroll
    for (int j = 0; j < 2; ++j) {
      const bf16x8 b0 = *(const bf16x8*)&Bs[cur][0][offB[j]];
#pragma unroll
      for (int i = 0; i < 4; ++i)
        acc0[i][j] = __builtin_amdgcn_mfma_f32_16x16x32_bf16(
            af[i], b0, acc0[i][j], 0, 0, 0);
      const bf16x8 b1 = *(const bf16x8*)&Bs[cur][1][offB[j]];
#pragma unroll
      for (int i = 0; i < 4; ++i)
        acc1[i][j] = __builtin_amdgcn_mfma_f32_16x16x32_bf16(
            af[i], b1, acc1[i][j], 0, 0, 0);
    }
    __builtin_amdgcn_s_setprio(0);

    if ((t & 15) == 15) {  // expert-pair epilogue (uniform branch)
      const int pair = t >> 4;
#pragma unroll
      for (int j = 0; j < 2; ++j) {
        const float bv0 = biasS[(2 * pair) * 64 + wn + j * 16 + lm];
        const float bv1 = biasS[(2 * pair + 1) * 64 + wn + j * 16 + lm];
#pragma unroll
        for (int i = 0; i < 4; ++i)
#pragma unroll
          for (int u = 0; u < 4; ++u) {
            sum[i][j][u] += fmaxf(acc0[i][j][u] + bv0, 0.f) +
                            fmaxf(acc1[i][j][u] + bv1, 0.f);
            acc0[i][j][u] = 0.f;
            acc1[i][j][u] = 0.f;
          }
      }
    }

    // T4: drain only own S(t+1); S(t+2),S(t+3) stay in flight across the
    // barrier. asm memory clobber + sched_barrier pin ds_reads inside phase.
    asm volatile("s_waitcnt vmcnt(8)" ::: "memory");
    __builtin_amdgcn_s_barrier();
    __builtin_amdgcn_sched_barrier(0);
  }
#undef STAGE

  // write: C/D layout col=lane&15, row=(lane>>4)*4+reg  [verified m89/m91]
  const int rbase = q * 4;
#pragma unroll
  for (int i = 0; i < 4; ++i)
#pragma unroll
    for (int j = 0; j < 2; ++j)
#pragma unroll
      for (int u = 0; u < 4; ++u)
        out[(size_t)(m0 + wm + i * 16 + rbase + u) * H_DIM + h0 + wn + j * 16 + lm] =
            sum[i][j][u];
}

// ---------------------------------------------------------------------------
// Fallback (only if workspace too small): naive but correct fp32.
// ---------------------------------------------------------------------------
__global__ __launch_bounds__(256) void naive_kernel(
    const float* __restrict__ x, const float* __restrict__ c,
    const float* __restrict__ W, const float* __restrict__ bias,
    float* __restrict__ out) {
  const int idx = blockIdx.x * 256 + threadIdx.x;
  const int b = idx >> 11;
  const int h = idx & (H_DIM - 1);
  const float* xr = x + (size_t)b * D_DIM;
  float s = 0.f;
  for (int e = 0; e < E_DIM; ++e) {
    const float* wr = W + ((size_t)e * H_DIM + h) * D_DIM;
    const float* cr = c + (size_t)e * D_DIM;
    float acc = bias[e * H_DIM + h];
    for (int d = 0; d < D_DIM; ++d) acc += (xr[d] - cr[d]) * wr[d];
    s += fmaxf(acc, 0.f);
  }
  out[idx] = s;
}

extern "C" void kernel_launch(void* const* d_in, const int* in_sizes, int n_in,
                              void* d_out, int out_size, void* d_ws, size_t ws_size,
                              hipStream_t stream) {
  const float* x = (const float*)d_in[0];     // [4096, 512]
  const float* c = (const float*)d_in[1];     // [16, 512]
  const float* W = (const float*)d_in[2];     // [16, 2048, 512]
  const float* b = (const float*)d_in[3];     // [16, 2048]
  float* out = (float*)d_out;                 // [4096, 2048]

  const size_t sz_wb = (size_t)E_DIM * H_DIM * D_DIM * 2;  // 32 MB
  const size_t sz_xb = (size_t)B_DIM * D_DIM * 2;          // 4 MB
  const size_t sz_b2 = (size_t)E_DIM * H_DIM * 4;          // 128 KB
  const size_t need = sz_wb + sz_xb + sz_b2;

  if (ws_size >= need) {
    __hip_bfloat16* Wb = (__hip_bfloat16*)((char*)d_ws);
    __hip_bfloat16* Xb = (__hip_bfloat16*)((char*)d_ws + sz_wb);
    float* bias2 = (float*)((char*)d_ws + sz_wb + sz_xb);
    prep<<<4608, 256, 0, stream>>>(W, c, b, x, Wb, bias2, Xb);
    moe_gemm<<<1024, 256, 0, stream>>>(Xb, Wb, bias2, out);
  } else {
    naive_kernel<<<(B_DIM * H_DIM) / 256, 256, 0, stream>>>(x, c, W, b, out);
  }
}

// Round 2
// 265.848 us; speedup vs baseline: 1.0790x; 1.0790x over previous
//
#include <hip/hip_runtime.h>
#include <hip/hip_bf16.h>
#include <stdint.h>
#include <stddef.h>

// Problem: B=4096, E=16, D=512, H=2048
// out[b,h] = sum_e relu( x_b . W[e,h,:] - c_e . W[e,h,:] + b[e,h] )
// GEMM view: M=4096, N=E*H (expert-looped), K=512. 137.4 GFLOP.
// R6: 128x64 tile, 2-expert pass, XOR-swizzled LDS (0 bank conflicts),
//     double-buffer + __syncthreads -> 165 us moe_gemm = 833 TF =
//     m97-structure ceiling (MfmaUtil 37.8%).
// R7 (FAILED): counted-vmcnt graft halved occupancy (2 blocks/CU), lost
//     cross-block overlap -> 197 us, MfmaUtil 29.6%. Reverted.
// R8: moe_gemm = R6 verbatim. prep rewritten fully-coalesced: every load
//     lane-contiguous 16B (1KB/instr/wave), every store lane-contiguous
//     8B bf16x4. Old prep had 64B lane stride = 25% per-instruction load
//     efficiency -> suspected cause of the ~90 us residual (floor ~17 us).

#define B_DIM 4096
#define E_DIM 16
#define D_DIM 512
#define H_DIM 2048

typedef short bf16x8 __attribute__((ext_vector_type(8)));
typedef short bf16x4 __attribute__((ext_vector_type(4)));
typedef float f32x4 __attribute__((ext_vector_type(4)));

__device__ __forceinline__ short f2bf(float f) {
  __hip_bfloat16 h = __float2bfloat16(f);  // RNE
  return *reinterpret_cast<short*>(&h);
}

__device__ __forceinline__ bf16x8 cvt8(float4 a, float4 b) {
  bf16x8 v;
  v[0] = f2bf(a.x); v[1] = f2bf(a.y); v[2] = f2bf(a.z); v[3] = f2bf(a.w);
  v[4] = f2bf(b.x); v[5] = f2bf(b.y); v[6] = f2bf(b.z); v[7] = f2bf(b.w);
  return v;
}

__device__ __forceinline__ bf16x4 cvt4(float4 a) {
  bf16x4 v;
  v[0] = f2bf(a.x); v[1] = f2bf(a.y); v[2] = f2bf(a.z); v[3] = f2bf(a.w);
  return v;
}

__device__ __forceinline__ float dot4(float4 a, float4 b) {
  return a.x * b.x + a.y * b.y + a.z * b.z + a.w * b.w;
}

// async global->LDS, 16 bytes per lane. LDS dest must be uniform_base + lane*16.
__device__ __forceinline__ void async_copy16(const void* gptr, void* lptr) {
  __builtin_amdgcn_global_load_lds(
      (const __attribute__((address_space(1))) void*)gptr,
      (__attribute__((address_space(3))) void*)lptr,
      16, 0, 0);
}

// ---------------------------------------------------------------------------
// Merged prepass, R8: fully-coalesced.
// W-pass, blocks [0,4096): wave wid owns rows 2*wid, 2*wid+1 = 1024
//   contiguous floats at W + wid*1024. Chunk j in 0..3: lane i loads float4
//   at wid*1024 + j*256 + i*4 (lane-contiguous 1KB per instruction).
//   Chunk j pairs with C half (j&1): C[e*512 + (j&1)*256 + i*4].
//   dot(row 2wid)   = full-wave sum of chunks 0,1;
//   dot(row 2wid+1) = full-wave sum of chunks 2,3.
//   Store bf16x4 (8B) per lane per chunk, lane-contiguous.
// X-pass, blocks [4096,5120): lane-contiguous float4 -> bf16x4, 2 chunks
//   per thread strided at grid level (both contiguous per instruction).
// ---------------------------------------------------------------------------
__global__ __launch_bounds__(256) void prep(
    const float* __restrict__ W, const float* __restrict__ C,
    const float* __restrict__ bias, const float* __restrict__ X,
    __hip_bfloat16* __restrict__ Wb, float* __restrict__ bias2,
    __hip_bfloat16* __restrict__ Xb) {
  if (blockIdx.x < 4096) {
    const int wid = (blockIdx.x * 256 + threadIdx.x) >> 6;  // wave 0..16383
    const int lane = threadIdx.x & 63;
    const int e = wid >> 10;  // 1024 waves (2048 rows) per expert
    const size_t base = (size_t)wid * 1024 + lane * 4;

    // C halves for this expert (uniform across wave -> broadcast-cached)
    const float4 cA = *(const float4*)(C + e * D_DIM + lane * 4);
    const float4 cB = *(const float4*)(C + e * D_DIM + 256 + lane * 4);

    float4 w0 = *(const float4*)(W + base);          // row 2wid   [0,256)
    float4 w1 = *(const float4*)(W + base + 256);    // row 2wid   [256,512)
    float4 w2 = *(const float4*)(W + base + 512);    // row 2wid+1 [0,256)
    float4 w3 = *(const float4*)(W + base + 768);    // row 2wid+1 [256,512)

    *(bf16x4*)(Wb + base) = cvt4(w0);
    *(bf16x4*)(Wb + base + 256) = cvt4(w1);
    *(bf16x4*)(Wb + base + 512) = cvt4(w2);
    *(bf16x4*)(Wb + base + 768) = cvt4(w3);

    float dot0 = dot4(w0, cA) + dot4(w1, cB);
    float dot1 = dot4(w2, cA) + dot4(w3, cB);
#pragma unroll
    for (int off = 32; off > 0; off >>= 1) {
      dot0 += __shfl_down(dot0, off, 64);
      dot1 += __shfl_down(dot1, off, 64);
    }
    if (lane == 0) {
      bias2[2 * wid] = bias[2 * wid] - dot0;
      bias2[2 * wid + 1] = bias[2 * wid + 1] - dot1;
    }
  } else {
    // X: 2,097,152 floats = 524,288 float4s; 262,144 threads x 2 chunks.
    const size_t t = (size_t)(blockIdx.x - 4096) * 256 + threadIdx.x;
    const size_t i0 = t * 4;
    const size_t i1 = i0 + (size_t)262144 * 4;
    float4 a0 = *(const float4*)(X + i0);
    float4 a1 = *(const float4*)(X + i1);
    *(bf16x4*)(Xb + i0) = cvt4(a0);
    *(bf16x4*)(Xb + i1) = cvt4(a1);
  }
}

// ---------------------------------------------------------------------------
// Main kernel (R6 structure, verified 165 us): tile m=128 x n=64, 4 waves
// (2m x 2n), wave = 64m x 32n per expert, 2 experts per K-pass (shared A
// fragments). A and both B tiles in LDS (double-buffered, one barrier per
// phase), XOR bank swizzle:
//   chunk slot (row, q) stores global k-chunk q ^ ((row>>1)&3).
// Staging: thread t writes LDS chunk t = (row=t>>2, slot q=t&3), fetching
// global k-chunk (t&3) ^ ((row>>1)&3). Rows r and r+64 share fr.
// Read side: fragment (row R, k-chunk q) found at slot q ^ ((R>>1)&3).
// LDS 36 KB, ~96 acc f32/thread => 4 blocks/CU. Grid 1024 (mi 32 x hi 32).
// SQ_LDS_BANK_CONFLICT == 0 measured.
// ---------------------------------------------------------------------------
__global__ __launch_bounds__(256, 4) void moe_gemm(
    const __hip_bfloat16* __restrict__ Xb,   // [4096, 512]
    const __hip_bfloat16* __restrict__ Wb,   // [16, 2048, 512]
    const float* __restrict__ bias2,         // [16, 2048]
    float* __restrict__ out) {               // [4096, 2048]
  __shared__ __align__(16) __hip_bfloat16 As[2][128 * 32];     // 16 KB
  __shared__ __align__(16) __hip_bfloat16 Bs[2][2][64 * 32];   // 16 KB
  __shared__ __align__(16) float biasS[E_DIM * 64];            // 4 KB

  const int tid = threadIdx.x;
  const int lane = tid & 63;
  const int wave = tid >> 6;
  const int hi = blockIdx.x & 31;
  const int mi = blockIdx.x >> 5;
  const int m0 = mi * 128;
  const int h0 = hi * 64;

  // preload bias2 for this h-tile (64 cols), all 16 experts
  for (int idx = tid; idx < E_DIM * 64; idx += 256) {
    biasS[idx] = bias2[((idx >> 6) << 11) + h0 + (idx & 63)];
  }

  const int wm = (wave & 1) * 64;
  const int wn = (wave >> 1) * 32;
  const int lm = lane & 15;
  const int q = lane >> 4;

  // ---- staging: thread t handles A chunks t,t+256 and B0/B1 chunk t.
  // Swizzled source: fetch global k-chunk (t&3) ^ ((row>>1)&3).
  const int r = tid >> 2;                       // rows 0..63
  const int fr = (r >> 1) & 3;                  // same for row r and r+64
  const int col = (((tid & 3) ^ fr)) << 3;      // swizzled k elem offset
  const size_t aOff0 = (size_t)(m0 + r) * D_DIM + col;
  const size_t aOff1 = (size_t)(m0 + r + 64) * D_DIM + col;
  const size_t bOff = (size_t)(h0 + r) * D_DIM + col;  // B rows 0..63
  const int ldA0 = tid * 8;
  const int ldA1 = (tid + 256) * 8;
  const int ldB = tid * 8;

  // ---- read-side element offsets: (row R, k-chunk q) at slot q^((R>>1)&3)
  int offA[4], offB[2];
#pragma unroll
  for (int i = 0; i < 4; ++i) {
    const int R = wm + i * 16 + lm;
    offA[i] = R * 32 + ((q ^ ((R >> 1) & 3)) << 3);
  }
#pragma unroll
  for (int j = 0; j < 2; ++j) {
    const int R = wn + j * 16 + lm;
    offB[j] = R * 32 + ((q ^ ((R >> 1) & 3)) << 3);
  }

  f32x4 sum[4][2], acc0[4][2], acc1[4][2];
#pragma unroll
  for (int i = 0; i < 4; ++i)
#pragma unroll
    for (int j = 0; j < 2; ++j) {
      sum[i][j] = (f32x4){0.f, 0.f, 0.f, 0.f};
      acc0[i][j] = (f32x4){0.f, 0.f, 0.f, 0.f};
      acc1[i][j] = (f32x4){0.f, 0.f, 0.f, 0.f};
    }

  // phase t: pair = t>>4, ks = t&15. stage(t) fills buffer t&1.
#define STAGE(buf, tt)                                                      \
  {                                                                         \
    const int kk = ((tt) & 15) << 5;                                        \
    const __hip_bfloat16* Bb = Wb + ((size_t)((tt) >> 4) << 21) + bOff + kk;\
    async_copy16(Xb + aOff0 + kk, &As[buf][ldA0]);                          \
    async_copy16(Xb + aOff1 + kk, &As[buf][ldA1]);                          \
    async_copy16(Bb, &Bs[buf][0][ldB]);                                     \
    async_copy16(Bb + ((size_t)1 << 20), &Bs[buf][1][ldB]);                 \
  }

  STAGE(0, 0);
  __syncthreads();  // buffer 0 ready

  for (int t = 0; t < 128; ++t) {
    const int cur = t & 1;
    if (t < 127) STAGE(cur ^ 1, t + 1);  // prefetch next phase

    bf16x8 af[4];
#pragma unroll
    for (int i = 0; i < 4; ++i) af[i] = *(const bf16x8*)&As[cur][offA[i]];

#pragma unroll
    for (int j = 0; j < 2; ++j) {
      const bf16x8 b0 = *(const bf16x8*)&Bs[cur][0][offB[j]];
#pragma unroll
      for (int i = 0; i < 4; ++i)
        acc0[i][j] = __builtin_amdgcn_mfma_f32_16x16x32_bf16(
            af[i], b0, acc0[i][j], 0, 0, 0);
      const bf16x8 b1 = *(const bf16x8*)&Bs[cur][1][offB[j]];
#pragma unroll
      for (int i = 0; i < 4; ++i)
        acc1[i][j] = __builtin_amdgcn_mfma_f32_16x16x32_bf16(
            af[i], b1, acc1[i][j], 0, 0, 0);
    }

    if ((t & 15) == 15) {  // expert-pair epilogue (uniform branch)
      const int pair = t >> 4;
#pragma unroll
      for (int j = 0; j < 2; ++j) {
        const float bv0 = biasS[(2 * pair) * 64 + wn + j * 16 + lm];
        const float bv1 = biasS[(2 * pair + 1) * 64 + wn + j * 16 + lm];
#pragma unroll
        for (int i = 0; i < 4; ++i)
#pragma unroll
          for (int u = 0; u < 4; ++u) {
            sum[i][j][u] += fmaxf(acc0[i][j][u] + bv0, 0.f) +
                            fmaxf(acc1[i][j][u] + bv1, 0.f);
            acc0[i][j][u] = 0.f;
            acc1[i][j][u] = 0.f;
          }
      }
    }

    __syncthreads();  // drains prefetch (overlapped); guards buf reuse
  }
#undef STAGE

  // write: C/D layout col=lane&15, row=(lane>>4)*4+reg  [verified m89/m91]
  const int rbase = q * 4;
#pragma unroll
  for (int i = 0; i < 4; ++i)
#pragma unroll
    for (int j = 0; j < 2; ++j)
#pragma unroll
      for (int u = 0; u < 4; ++u)
        out[(size_t)(m0 + wm + i * 16 + rbase + u) * H_DIM + h0 + wn + j * 16 + lm] =
            sum[i][j][u];
}

// ---------------------------------------------------------------------------
// Fallback (only if workspace too small): naive but correct fp32.
// ---------------------------------------------------------------------------
__global__ __launch_bounds__(256) void naive_kernel(
    const float* __restrict__ x, const float* __restrict__ c,
    const float* __restrict__ W, const float* __restrict__ bias,
    float* __restrict__ out) {
  const int idx = blockIdx.x * 256 + threadIdx.x;
  const int b = idx >> 11;
  const int h = idx & (H_DIM - 1);
  const float* xr = x + (size_t)b * D_DIM;
  float s = 0.f;
  for (int e = 0; e < E_DIM; ++e) {
    const float* wr = W + ((size_t)e * H_DIM + h) * D_DIM;
    const float* cr = c + (size_t)e * D_DIM;
    float acc = bias[e * H_DIM + h];
    for (int d = 0; d < D_DIM; ++d) acc += (xr[d] - cr[d]) * wr[d];
    s += fmaxf(acc, 0.f);
  }
  out[idx] = s;
}

extern "C" void kernel_launch(void* const* d_in, const int* in_sizes, int n_in,
                              void* d_out, int out_size, void* d_ws, size_t ws_size,
                              hipStream_t stream) {
  const float* x = (const float*)d_in[0];     // [4096, 512]
  const float* c = (const float*)d_in[1];     // [16, 512]
  const float* W = (const float*)d_in[2];     // [16, 2048, 512]
  const float* b = (const float*)d_in[3];     // [16, 2048]
  float* out = (float*)d_out;                 // [4096, 2048]

  const size_t sz_wb = (size_t)E_DIM * H_DIM * D_DIM * 2;  // 32 MB
  const size_t sz_xb = (size_t)B_DIM * D_DIM * 2;          // 4 MB
  const size_t sz_b2 = (size_t)E_DIM * H_DIM * 4;          // 128 KB
  const size_t need = sz_wb + sz_xb + sz_b2;

  if (ws_size >= need) {
    __hip_bfloat16* Wb = (__hip_bfloat16*)((char*)d_ws);
    __hip_bfloat16* Xb = (__hip_bfloat16*)((char*)d_ws + sz_wb);
    float* bias2 = (float*)((char*)d_ws + sz_wb + sz_xb);
    prep<<<5120, 256, 0, stream>>>(W, c, b, x, Wb, bias2, Xb);
    moe_gemm<<<1024, 256, 0, stream>>>(Xb, Wb, bias2, out);
  } else {
    naive_kernel<<<(B_DIM * H_DIM) / 256, 256, 0, stream>>>(x, c, W, b, out);
  }
}

// Round 3
// 262.299 us; speedup vs baseline: 1.0936x; 1.0135x over previous
//
#include <hip/hip_runtime.h>
#include <hip/hip_bf16.h>
#include <hip/hip_cooperative_groups.h>
#include <stdint.h>
#include <stddef.h>

// Problem: B=4096, E=16, D=512, H=2048
// out[b,h] = sum_e relu( x_b . W[e,h,:] - c_e . W[e,h,:] + b[e,h] )
// GEMM view: M=4096, N=E*H (expert-looped), K=512. 137.4 GFLOP.
// R6: 128x64 tile GEMM, XOR-swizzled LDS (0 conflicts), dbuf+syncthreads
//     -> 167 us = m97-structure ceiling (MfmaUtil ~38%).
// R7 (FAILED): counted-vmcnt graft -> occupancy loss, 197 us. Reverted.
// R8: coalesced prep -> residual UNCHANGED (~95 us across 3 prep variants).
//     => residual is NOT prep's access pattern. Either invisible-but-slow
//     prep or inter-kernel overhead; two-kernel split can't distinguish.
// R9: single cooperative kernel: prep slice + grid.sync + R6 gemm phase.
//     Grid 1024x256 = exactly 4 blocks/CU (LDS 36.8KB, VGPR<=128 via
//     launch_bounds(256,4)) x 256 CU. Makes 100% of device time visible
//     in one dispatch; removes one launch + inter-kernel gap.

namespace cg = cooperative_groups;

#define B_DIM 4096
#define E_DIM 16
#define D_DIM 512
#define H_DIM 2048

typedef short bf16x8 __attribute__((ext_vector_type(8)));
typedef short bf16x4 __attribute__((ext_vector_type(4)));
typedef float f32x4 __attribute__((ext_vector_type(4)));

__device__ __forceinline__ short f2bf(float f) {
  __hip_bfloat16 h = __float2bfloat16(f);  // RNE
  return *reinterpret_cast<short*>(&h);
}

__device__ __forceinline__ bf16x4 cvt4(float4 a) {
  bf16x4 v;
  v[0] = f2bf(a.x); v[1] = f2bf(a.y); v[2] = f2bf(a.z); v[3] = f2bf(a.w);
  return v;
}

__device__ __forceinline__ float dot4(float4 a, float4 b) {
  return a.x * b.x + a.y * b.y + a.z * b.z + a.w * b.w;
}

// async global->LDS, 16 bytes per lane. LDS dest must be uniform_base + lane*16.
__device__ __forceinline__ void async_copy16(const void* gptr, void* lptr) {
  __builtin_amdgcn_global_load_lds(
      (const __attribute__((address_space(1))) void*)gptr,
      (__attribute__((address_space(3))) void*)lptr,
      16, 0, 0);
}

// ---------------------------------------------------------------------------
// R9 fused cooperative kernel. Phase 1 (prep): each of 1024 blocks converts
// its slice of W (wave w of 4096 handles row-pairs 4w..4w+3, fully coalesced:
// lane-contiguous float4 loads / bf16x4 stores) + bias2 dots + an X slice
// (8 floats/thread). Phase 2 after grid.sync(): R6-verified GEMM.
// ---------------------------------------------------------------------------
__global__ __launch_bounds__(256, 4) void fused(
    const float* __restrict__ X, const float* __restrict__ C,
    const float* __restrict__ W, const float* __restrict__ bias,
    __hip_bfloat16* Wb, float* bias2, __hip_bfloat16* Xb,
    float* __restrict__ out) {
  __shared__ __align__(16) __hip_bfloat16 As[2][128 * 32];     // 16 KB
  __shared__ __align__(16) __hip_bfloat16 Bs[2][2][64 * 32];   // 16 KB
  __shared__ __align__(16) float biasS[E_DIM * 64];            // 4 KB

  const int tid = threadIdx.x;
  const int bid = blockIdx.x;
  const int lane = tid & 63;
  const int wave = tid >> 6;

  // ===================== phase 1: prep slice =====================
  {
    // X: 2,097,152 floats over 262,144 threads = 8 floats/thread.
    const size_t tt = (size_t)bid * 256 + tid;
    const size_t i0 = tt * 8;
    float4 a0 = *(const float4*)(X + i0);
    float4 a1 = *(const float4*)(X + i0 + 4);
    *(bf16x4*)(Xb + i0) = cvt4(a0);
    *(bf16x4*)(Xb + i0 + 4) = cvt4(a1);

    // W: global wave gw in [0,4096); row-pair ids wid = 4*gw..4*gw+3,
    // each covering rows 2*wid, 2*wid+1 = 1024 contiguous floats.
    const int gw = (bid << 2) + wave;
    for (int it = 0; it < 4; ++it) {
      const int wid = (gw << 2) + it;  // 0..16383
      const int e = wid >> 10;         // expert (1024 row-pairs per expert)
      const size_t base = (size_t)wid * 1024 + lane * 4;

      const float4 cA = *(const float4*)(C + e * D_DIM + lane * 4);
      const float4 cB = *(const float4*)(C + e * D_DIM + 256 + lane * 4);

      float4 w0 = *(const float4*)(W + base);          // row 2wid   [0,256)
      float4 w1 = *(const float4*)(W + base + 256);    // row 2wid   [256,512)
      float4 w2 = *(const float4*)(W + base + 512);    // row 2wid+1 [0,256)
      float4 w3 = *(const float4*)(W + base + 768);    // row 2wid+1 [256,512)

      *(bf16x4*)(Wb + base) = cvt4(w0);
      *(bf16x4*)(Wb + base + 256) = cvt4(w1);
      *(bf16x4*)(Wb + base + 512) = cvt4(w2);
      *(bf16x4*)(Wb + base + 768) = cvt4(w3);

      float dot0 = dot4(w0, cA) + dot4(w1, cB);
      float dot1 = dot4(w2, cA) + dot4(w3, cB);
#pragma unroll
      for (int off = 32; off > 0; off >>= 1) {
        dot0 += __shfl_down(dot0, off, 64);
        dot1 += __shfl_down(dot1, off, 64);
      }
      if (lane == 0) {
        bias2[2 * wid] = bias[2 * wid] - dot0;
        bias2[2 * wid + 1] = bias[2 * wid + 1] - dot1;
      }
    }
  }

  cg::this_grid().sync();  // device-scope fence + grid barrier (cross-XCD)

  // ===================== phase 2: GEMM (R6 verified) =====================
  const int hi = bid & 31;
  const int mi = bid >> 5;
  const int m0 = mi * 128;
  const int h0 = hi * 64;

  // preload bias2 for this h-tile (64 cols), all 16 experts
  for (int idx = tid; idx < E_DIM * 64; idx += 256) {
    biasS[idx] = bias2[((idx >> 6) << 11) + h0 + (idx & 63)];
  }

  const int wm = (wave & 1) * 64;
  const int wn = (wave >> 1) * 32;
  const int lm = lane & 15;
  const int q = lane >> 4;

  // staging: thread t handles A chunks t,t+256 and B0/B1 chunk t.
  // Swizzled source: fetch global k-chunk (t&3) ^ ((row>>1)&3).
  const int r = tid >> 2;                       // rows 0..63
  const int fr = (r >> 1) & 3;                  // same for row r and r+64
  const int col = (((tid & 3) ^ fr)) << 3;      // swizzled k elem offset
  const size_t aOff0 = (size_t)(m0 + r) * D_DIM + col;
  const size_t aOff1 = (size_t)(m0 + r + 64) * D_DIM + col;
  const size_t bOff = (size_t)(h0 + r) * D_DIM + col;  // B rows 0..63
  const int ldA0 = tid * 8;
  const int ldA1 = (tid + 256) * 8;
  const int ldB = tid * 8;

  // read-side element offsets: (row R, k-chunk q) at slot q^((R>>1)&3)
  int offA[4], offB[2];
#pragma unroll
  for (int i = 0; i < 4; ++i) {
    const int R = wm + i * 16 + lm;
    offA[i] = R * 32 + ((q ^ ((R >> 1) & 3)) << 3);
  }
#pragma unroll
  for (int j = 0; j < 2; ++j) {
    const int R = wn + j * 16 + lm;
    offB[j] = R * 32 + ((q ^ ((R >> 1) & 3)) << 3);
  }

  f32x4 sum[4][2], acc0[4][2], acc1[4][2];
#pragma unroll
  for (int i = 0; i < 4; ++i)
#pragma unroll
    for (int j = 0; j < 2; ++j) {
      sum[i][j] = (f32x4){0.f, 0.f, 0.f, 0.f};
      acc0[i][j] = (f32x4){0.f, 0.f, 0.f, 0.f};
      acc1[i][j] = (f32x4){0.f, 0.f, 0.f, 0.f};
    }

  // phase t: pair = t>>4, ks = t&15. stage(t) fills buffer t&1.
#define STAGE(buf, tt)                                                      \
  {                                                                         \
    const int kk = ((tt) & 15) << 5;                                        \
    const __hip_bfloat16* Bb = Wb + ((size_t)((tt) >> 4) << 21) + bOff + kk;\
    async_copy16(Xb + aOff0 + kk, &As[buf][ldA0]);                          \
    async_copy16(Xb + aOff1 + kk, &As[buf][ldA1]);                          \
    async_copy16(Bb, &Bs[buf][0][ldB]);                                     \
    async_copy16(Bb + ((size_t)1 << 20), &Bs[buf][1][ldB]);                 \
  }

  STAGE(0, 0);
  __syncthreads();  // buffer 0 ready

  for (int t = 0; t < 128; ++t) {
    const int cur = t & 1;
    if (t < 127) STAGE(cur ^ 1, t + 1);  // prefetch next phase

    bf16x8 af[4];
#pragma unroll
    for (int i = 0; i < 4; ++i) af[i] = *(const bf16x8*)&As[cur][offA[i]];

#pragma unroll
    for (int j = 0; j < 2; ++j) {
      const bf16x8 b0 = *(const bf16x8*)&Bs[cur][0][offB[j]];
#pragma unroll
      for (int i = 0; i < 4; ++i)
        acc0[i][j] = __builtin_amdgcn_mfma_f32_16x16x32_bf16(
            af[i], b0, acc0[i][j], 0, 0, 0);
      const bf16x8 b1 = *(const bf16x8*)&Bs[cur][1][offB[j]];
#pragma unroll
      for (int i = 0; i < 4; ++i)
        acc1[i][j] = __builtin_amdgcn_mfma_f32_16x16x32_bf16(
            af[i], b1, acc1[i][j], 0, 0, 0);
    }

    if ((t & 15) == 15) {  // expert-pair epilogue (uniform branch)
      const int pair = t >> 4;
#pragma unroll
      for (int j = 0; j < 2; ++j) {
        const float bv0 = biasS[(2 * pair) * 64 + wn + j * 16 + lm];
        const float bv1 = biasS[(2 * pair + 1) * 64 + wn + j * 16 + lm];
#pragma unroll
        for (int i = 0; i < 4; ++i)
#pragma unroll
          for (int u = 0; u < 4; ++u) {
            sum[i][j][u] += fmaxf(acc0[i][j][u] + bv0, 0.f) +
                            fmaxf(acc1[i][j][u] + bv1, 0.f);
            acc0[i][j][u] = 0.f;
            acc1[i][j][u] = 0.f;
          }
      }
    }

    __syncthreads();  // drains prefetch (overlapped); guards buf reuse
  }
#undef STAGE

  // write: C/D layout col=lane&15, row=(lane>>4)*4+reg  [verified m89/m91]
  const int rbase = q * 4;
#pragma unroll
  for (int i = 0; i < 4; ++i)
#pragma unroll
    for (int j = 0; j < 2; ++j)
#pragma unroll
      for (int u = 0; u < 4; ++u)
        out[(size_t)(m0 + wm + i * 16 + rbase + u) * H_DIM + h0 + wn + j * 16 + lm] =
            sum[i][j][u];
}

// ---------------------------------------------------------------------------
// Fallback path A (if cooperative occupancy check fails): R8 two-kernel.
// ---------------------------------------------------------------------------
__global__ __launch_bounds__(256) void prep(
    const float* __restrict__ W, const float* __restrict__ C,
    const float* __restrict__ bias, const float* __restrict__ X,
    __hip_bfloat16* __restrict__ Wb, float* __restrict__ bias2,
    __hip_bfloat16* __restrict__ Xb) {
  if (blockIdx.x < 4096) {
    const int wid = (blockIdx.x * 256 + threadIdx.x) >> 6;  // wave 0..16383
    const int lane = threadIdx.x & 63;
    const int e = wid >> 10;
    const size_t base = (size_t)wid * 1024 + lane * 4;
    const float4 cA = *(const float4*)(C + e * D_DIM + lane * 4);
    const float4 cB = *(const float4*)(C + e * D_DIM + 256 + lane * 4);
    float4 w0 = *(const float4*)(W + base);
    float4 w1 = *(const float4*)(W + base + 256);
    float4 w2 = *(const float4*)(W + base + 512);
    float4 w3 = *(const float4*)(W + base + 768);
    *(bf16x4*)(Wb + base) = cvt4(w0);
    *(bf16x4*)(Wb + base + 256) = cvt4(w1);
    *(bf16x4*)(Wb + base + 512) = cvt4(w2);
    *(bf16x4*)(Wb + base + 768) = cvt4(w3);
    float dot0 = dot4(w0, cA) + dot4(w1, cB);
    float dot1 = dot4(w2, cA) + dot4(w3, cB);
#pragma unroll
    for (int off = 32; off > 0; off >>= 1) {
      dot0 += __shfl_down(dot0, off, 64);
      dot1 += __shfl_down(dot1, off, 64);
    }
    if (lane == 0) {
      bias2[2 * wid] = bias[2 * wid] - dot0;
      bias2[2 * wid + 1] = bias[2 * wid + 1] - dot1;
    }
  } else {
    const size_t t = (size_t)(blockIdx.x - 4096) * 256 + threadIdx.x;
    const size_t i0 = t * 4;
    const size_t i1 = i0 + (size_t)262144 * 4;
    float4 a0 = *(const float4*)(X + i0);
    float4 a1 = *(const float4*)(X + i1);
    *(bf16x4*)(Xb + i0) = cvt4(a0);
    *(bf16x4*)(Xb + i1) = cvt4(a1);
  }
}

__global__ __launch_bounds__(256, 4) void moe_gemm(
    const __hip_bfloat16* __restrict__ Xb, const __hip_bfloat16* __restrict__ Wb,
    const float* __restrict__ bias2, float* __restrict__ out) {
  __shared__ __align__(16) __hip_bfloat16 As[2][128 * 32];
  __shared__ __align__(16) __hip_bfloat16 Bs[2][2][64 * 32];
  __shared__ __align__(16) float biasS[E_DIM * 64];

  const int tid = threadIdx.x;
  const int lane = tid & 63;
  const int wave = tid >> 6;
  const int hi = blockIdx.x & 31;
  const int mi = blockIdx.x >> 5;
  const int m0 = mi * 128;
  const int h0 = hi * 64;

  for (int idx = tid; idx < E_DIM * 64; idx += 256) {
    biasS[idx] = bias2[((idx >> 6) << 11) + h0 + (idx & 63)];
  }

  const int wm = (wave & 1) * 64;
  const int wn = (wave >> 1) * 32;
  const int lm = lane & 15;
  const int q = lane >> 4;

  const int r = tid >> 2;
  const int fr = (r >> 1) & 3;
  const int col = (((tid & 3) ^ fr)) << 3;
  const size_t aOff0 = (size_t)(m0 + r) * D_DIM + col;
  const size_t aOff1 = (size_t)(m0 + r + 64) * D_DIM + col;
  const size_t bOff = (size_t)(h0 + r) * D_DIM + col;
  const int ldA0 = tid * 8;
  const int ldA1 = (tid + 256) * 8;
  const int ldB = tid * 8;

  int offA[4], offB[2];
#pragma unroll
  for (int i = 0; i < 4; ++i) {
    const int R = wm + i * 16 + lm;
    offA[i] = R * 32 + ((q ^ ((R >> 1) & 3)) << 3);
  }
#pragma unroll
  for (int j = 0; j < 2; ++j) {
    const int R = wn + j * 16 + lm;
    offB[j] = R * 32 + ((q ^ ((R >> 1) & 3)) << 3);
  }

  f32x4 sum[4][2], acc0[4][2], acc1[4][2];
#pragma unroll
  for (int i = 0; i < 4; ++i)
#pragma unroll
    for (int j = 0; j < 2; ++j) {
      sum[i][j] = (f32x4){0.f, 0.f, 0.f, 0.f};
      acc0[i][j] = (f32x4){0.f, 0.f, 0.f, 0.f};
      acc1[i][j] = (f32x4){0.f, 0.f, 0.f, 0.f};
    }

#define STAGE(buf, tt)                                                      \
  {                                                                         \
    const int kk = ((tt) & 15) << 5;                                        \
    const __hip_bfloat16* Bb = Wb + ((size_t)((tt) >> 4) << 21) + bOff + kk;\
    async_copy16(Xb + aOff0 + kk, &As[buf][ldA0]);                          \
    async_copy16(Xb + aOff1 + kk, &As[buf][ldA1]);                          \
    async_copy16(Bb, &Bs[buf][0][ldB]);                                     \
    async_copy16(Bb + ((size_t)1 << 20), &Bs[buf][1][ldB]);                 \
  }

  STAGE(0, 0);
  __syncthreads();

  for (int t = 0; t < 128; ++t) {
    const int cur = t & 1;
    if (t < 127) STAGE(cur ^ 1, t + 1);

    bf16x8 af[4];
#pragma unroll
    for (int i = 0; i < 4; ++i) af[i] = *(const bf16x8*)&As[cur][offA[i]];

#pragma unroll
    for (int j = 0; j < 2; ++j) {
      const bf16x8 b0 = *(const bf16x8*)&Bs[cur][0][offB[j]];
#pragma unroll
      for (int i = 0; i < 4; ++i)
        acc0[i][j] = __builtin_amdgcn_mfma_f32_16x16x32_bf16(
            af[i], b0, acc0[i][j], 0, 0, 0);
      const bf16x8 b1 = *(const bf16x8*)&Bs[cur][1][offB[j]];
#pragma unroll
      for (int i = 0; i < 4; ++i)
        acc1[i][j] = __builtin_amdgcn_mfma_f32_16x16x32_bf16(
            af[i], b1, acc1[i][j], 0, 0, 0);
    }

    if ((t & 15) == 15) {
      const int pair = t >> 4;
#pragma unroll
      for (int j = 0; j < 2; ++j) {
        const float bv0 = biasS[(2 * pair) * 64 + wn + j * 16 + lm];
        const float bv1 = biasS[(2 * pair + 1) * 64 + wn + j * 16 + lm];
#pragma unroll
        for (int i = 0; i < 4; ++i)
#pragma unroll
          for (int u = 0; u < 4; ++u) {
            sum[i][j][u] += fmaxf(acc0[i][j][u] + bv0, 0.f) +
                            fmaxf(acc1[i][j][u] + bv1, 0.f);
            acc0[i][j][u] = 0.f;
            acc1[i][j][u] = 0.f;
          }
      }
    }

    __syncthreads();
  }
#undef STAGE

  const int rbase = q * 4;
#pragma unroll
  for (int i = 0; i < 4; ++i)
#pragma unroll
    for (int j = 0; j < 2; ++j)
#pragma unroll
      for (int u = 0; u < 4; ++u)
        out[(size_t)(m0 + wm + i * 16 + rbase + u) * H_DIM + h0 + wn + j * 16 + lm] =
            sum[i][j][u];
}

// ---------------------------------------------------------------------------
// Fallback path B (workspace too small): naive fp32.
// ---------------------------------------------------------------------------
__global__ __launch_bounds__(256) void naive_kernel(
    const float* __restrict__ x, const float* __restrict__ c,
    const float* __restrict__ W, const float* __restrict__ bias,
    float* __restrict__ out) {
  const int idx = blockIdx.x * 256 + threadIdx.x;
  const int b = idx >> 11;
  const int h = idx & (H_DIM - 1);
  const float* xr = x + (size_t)b * D_DIM;
  float s = 0.f;
  for (int e = 0; e < E_DIM; ++e) {
    const float* wr = W + ((size_t)e * H_DIM + h) * D_DIM;
    const float* cr = c + (size_t)e * D_DIM;
    float acc = bias[e * H_DIM + h];
    for (int d = 0; d < D_DIM; ++d) acc += (xr[d] - cr[d]) * wr[d];
    s += fmaxf(acc, 0.f);
  }
  out[idx] = s;
}

extern "C" void kernel_launch(void* const* d_in, const int* in_sizes, int n_in,
                              void* d_out, int out_size, void* d_ws, size_t ws_size,
                              hipStream_t stream) {
  const float* x = (const float*)d_in[0];     // [4096, 512]
  const float* c = (const float*)d_in[1];     // [16, 512]
  const float* W = (const float*)d_in[2];     // [16, 2048, 512]
  const float* b = (const float*)d_in[3];     // [16, 2048]
  float* out = (float*)d_out;                 // [4096, 2048]

  const size_t sz_wb = (size_t)E_DIM * H_DIM * D_DIM * 2;  // 32 MB
  const size_t sz_xb = (size_t)B_DIM * D_DIM * 2;          // 4 MB
  const size_t sz_b2 = (size_t)E_DIM * H_DIM * 4;          // 128 KB
  const size_t need = sz_wb + sz_xb + sz_b2;

  if (ws_size >= need) {
    __hip_bfloat16* Wb = (__hip_bfloat16*)((char*)d_ws);
    __hip_bfloat16* Xb = (__hip_bfloat16*)((char*)d_ws + sz_wb);
    float* bias2 = (float*)((char*)d_ws + sz_wb + sz_xb);

    // One-time static check: can 1024 blocks be co-resident (4/CU x 256 CU)?
    static int coop_ok = -1;
    if (coop_ok < 0) {
      int nb = 0;
      hipError_t e =
          hipOccupancyMaxActiveBlocksPerMultiprocessor(&nb, fused, 256, 0);
      coop_ok = (e == hipSuccess && nb >= 4) ? 1 : 0;
    }

    if (coop_ok) {
      void* args[] = {(void*)&x, (void*)&c, (void*)&W, (void*)&b,
                      (void*)&Wb, (void*)&bias2, (void*)&Xb, (void*)&out};
      hipLaunchCooperativeKernel(fused, dim3(1024), dim3(256), args, 0, stream);
    } else {
      prep<<<5120, 256, 0, stream>>>(W, c, b, x, Wb, bias2, Xb);
      moe_gemm<<<1024, 256, 0, stream>>>(Xb, Wb, bias2, out);
    }
  } else {
    naive_kernel<<<(B_DIM * H_DIM) / 256, 256, 0, stream>>>(x, c, W, b, out);
  }
}

// Round 4
// 262.235 us; speedup vs baseline: 1.0939x; 1.0002x over previous
//
#include <hip/hip_runtime.h>
#include <hip/hip_bf16.h>
#include <stdint.h>
#include <stddef.h>

// Problem: B=4096, E=16, D=512, H=2048
// out[b,h] = sum_e relu( x_b . W[e,h,:] - c_e . W[e,h,:] + b[e,h] )
// GEMM view: M=4096, N=E*H (expert-looped), K=512. 137.4 GFLOP.
// R6: 128x64 tile, 2-expert pass, xor-swizzle, dbuf+syncthreads: 167 us
//     (drain-stall-bound; staging 2.1 GB/iter is NOT the binder).
// R7 (FAILED): counted vmcnt + 4 small buffers -> occupancy 4->2 blocks/CU,
//     lost cross-block overlap. Lesson: counted-vmcnt needs a structure
//     designed for 1-block/CU, not a graft.
// R8/R9: prep residual ~95 us invariant across 4 implementations and
//     fusion -> stop attacking prep.
// R10: moe_gemm8 = template-regime GEMM: 512 thr, 1 block/CU, tile 256x128,
//     BK=64, 8 waves (4Mx2N, 64x64/wave), 3 LDS buffers (144KB) so
//     s_waitcnt vmcnt(6) keeps 2 stages in flight across every barrier
//     (FIFO at tile end = {g+1:6, g+2:6}; vmcnt(6) drains exactly g+1).
//     Single expert per pass; relu-merge at K-tile boundaries (g&7==7).
//     Swizzle: LDS slot = chunk ^ (row&7) (BK=64 rows = 128B); per
//     16-lane quarter: 8 slots x 2 lanes = conflict-free (R6-verified
//     family). R6 kernel kept as runtime fallback.

#define B_DIM 4096
#define E_DIM 16
#define D_DIM 512
#define H_DIM 2048

typedef short bf16x8 __attribute__((ext_vector_type(8)));
typedef short bf16x4 __attribute__((ext_vector_type(4)));
typedef float f32x4 __attribute__((ext_vector_type(4)));

__device__ __forceinline__ short f2bf(float f) {
  __hip_bfloat16 h = __float2bfloat16(f);  // RNE
  return *reinterpret_cast<short*>(&h);
}

__device__ __forceinline__ bf16x4 cvt4(float4 a) {
  bf16x4 v;
  v[0] = f2bf(a.x); v[1] = f2bf(a.y); v[2] = f2bf(a.z); v[3] = f2bf(a.w);
  return v;
}

__device__ __forceinline__ float dot4(float4 a, float4 b) {
  return a.x * b.x + a.y * b.y + a.z * b.z + a.w * b.w;
}

// async global->LDS, 16 bytes per lane. LDS dest must be uniform_base + lane*16.
__device__ __forceinline__ void async_copy16(const void* gptr, void* lptr) {
  __builtin_amdgcn_global_load_lds(
      (const __attribute__((address_space(1))) void*)gptr,
      (__attribute__((address_space(3))) void*)lptr,
      16, 0, 0);
}

// ---------------------------------------------------------------------------
// Prepass (R8, coalesced). W-pass blocks [0,4096): wave owns 2 rows = 1024
// contiguous floats; X-pass blocks [4096,5120).
// ---------------------------------------------------------------------------
__global__ __launch_bounds__(256) void prep(
    const float* __restrict__ W, const float* __restrict__ C,
    const float* __restrict__ bias, const float* __restrict__ X,
    __hip_bfloat16* __restrict__ Wb, float* __restrict__ bias2,
    __hip_bfloat16* __restrict__ Xb) {
  if (blockIdx.x < 4096) {
    const int wid = (blockIdx.x * 256 + threadIdx.x) >> 6;  // wave 0..16383
    const int lane = threadIdx.x & 63;
    const int e = wid >> 10;
    const size_t base = (size_t)wid * 1024 + lane * 4;
    const float4 cA = *(const float4*)(C + e * D_DIM + lane * 4);
    const float4 cB = *(const float4*)(C + e * D_DIM + 256 + lane * 4);
    float4 w0 = *(const float4*)(W + base);
    float4 w1 = *(const float4*)(W + base + 256);
    float4 w2 = *(const float4*)(W + base + 512);
    float4 w3 = *(const float4*)(W + base + 768);
    *(bf16x4*)(Wb + base) = cvt4(w0);
    *(bf16x4*)(Wb + base + 256) = cvt4(w1);
    *(bf16x4*)(Wb + base + 512) = cvt4(w2);
    *(bf16x4*)(Wb + base + 768) = cvt4(w3);
    float dot0 = dot4(w0, cA) + dot4(w1, cB);
    float dot1 = dot4(w2, cA) + dot4(w3, cB);
#pragma unroll
    for (int off = 32; off > 0; off >>= 1) {
      dot0 += __shfl_down(dot0, off, 64);
      dot1 += __shfl_down(dot1, off, 64);
    }
    if (lane == 0) {
      bias2[2 * wid] = bias[2 * wid] - dot0;
      bias2[2 * wid + 1] = bias[2 * wid + 1] - dot1;
    }
  } else {
    const size_t t = (size_t)(blockIdx.x - 4096) * 256 + threadIdx.x;
    const size_t i0 = t * 4;
    const size_t i1 = i0 + (size_t)262144 * 4;
    float4 a0 = *(const float4*)(X + i0);
    float4 a1 = *(const float4*)(X + i1);
    *(bf16x4*)(Xb + i0) = cvt4(a0);
    *(bf16x4*)(Xb + i1) = cvt4(a1);
  }
}

// ---------------------------------------------------------------------------
// R10 main GEMM. Tile 256x128, BK=64, 512 thr, 8 waves (4Mx2N), 64x64/wave.
// K-tiles g = e*8 + k, g in [0,128). Buffers rotate mod 3 (48KB each).
// Half-iteration g: STAGE(g+2) -> ds_read+MFMA (2 k-steps) -> merge at
// expert end -> vmcnt(6) -> s_barrier.
// LDS layout per buffer: A [256 rows][8 slots of 16B] (32KB), B at +32768
// [128][8 slots] (16KB). Slot s of row r holds k-chunk s^(r&7).
// biasS (16 experts x 128 cols, f32) at byte 147456. Total 155648 B.
// ---------------------------------------------------------------------------
__global__ __launch_bounds__(512, 2) void moe_gemm8(
    const __hip_bfloat16* __restrict__ Xb,   // [4096, 512]
    const __hip_bfloat16* __restrict__ Wb,   // [16, 2048, 512]
    const float* __restrict__ bias2,         // [16, 2048]
    float* __restrict__ out) {               // [4096, 2048]
  __shared__ __align__(16) char smem[155648];

  const int tid = threadIdx.x;
  const int lane = tid & 63;
  const int wave = tid >> 6;

  // bijective XCD swizzle (m204): nwg=256, 32 per XCD.
  const int swz = (blockIdx.x & 7) * 32 + (blockIdx.x >> 3);
  const int mi = swz >> 4;          // 16 m-tiles
  const int hi = swz & 15;          // 16 h-tiles
  const int m0 = mi * 256;
  const int h0 = hi * 128;

  const int wm = (wave >> 1) * 64;  // 4 m-groups
  const int wn = (wave & 1) * 64;   // 2 n-groups
  const int lm = lane & 15;
  const int q = lane >> 4;

  // ---- staging source offsets (pre-swizzled): chunk id n -> row n>>3,
  // slot n&7 holds global chunk (n&7)^(row&7).
  int aSrc[4], bSrc[2];
#pragma unroll
  for (int j = 0; j < 4; ++j) {
    const int n = j * 512 + tid;
    const int r = n >> 3;
    const int c = (n & 7) ^ (r & 7);
    aSrc[j] = r * D_DIM + c * 8;
  }
#pragma unroll
  for (int j = 0; j < 2; ++j) {
    const int n = j * 512 + tid;
    const int r = n >> 3;
    const int c = (n & 7) ^ (r & 7);
    bSrc[j] = r * D_DIM + c * 8;
  }

  // ---- read-side byte offsets within a buffer: frag (row R, k-step s):
  // chunk c = s*4+q at slot c^(R&7).
  int aRd[4][2], bRd[4][2];
#pragma unroll
  for (int m = 0; m < 4; ++m) {
    const int R = wm + m * 16 + lm;
#pragma unroll
    for (int s = 0; s < 2; ++s)
      aRd[m][s] = R * 128 + (((s * 4 + q) ^ (R & 7)) << 4);
  }
#pragma unroll
  for (int n = 0; n < 4; ++n) {
    const int R = wn + n * 16 + lm;
#pragma unroll
    for (int s = 0; s < 2; ++s)
      bRd[n][s] = 32768 + R * 128 + (((s * 4 + q) ^ (R & 7)) << 4);
  }

#define STAGE8(bufOff, gg)                                                   \
  {                                                                          \
    const int eS = (gg) >> 3;                                                \
    const int k0 = ((gg) & 7) << 6;                                          \
    const __hip_bfloat16* Ag = Xb + (size_t)m0 * D_DIM + k0;                 \
    const __hip_bfloat16* Bg =                                               \
        Wb + ((size_t)eS << 20) + (size_t)h0 * D_DIM + k0;                   \
    _Pragma("unroll")                                                        \
    for (int j = 0; j < 4; ++j)                                              \
      async_copy16(Ag + aSrc[j], smem + (bufOff) + (j * 512 + tid) * 16);    \
    _Pragma("unroll")                                                        \
    for (int j = 0; j < 2; ++j)                                              \
      async_copy16(Bg + bSrc[j],                                             \
                   smem + (bufOff) + 32768 + (j * 512 + tid) * 16);          \
  }

  // ---- prologue: bias preload + stage tiles 0,1.
  STAGE8(0, 0);
  STAGE8(49152, 1);
  {
    float* bS = (float*)(smem + 147456);
#pragma unroll
    for (int j = 0; j < 4; ++j) {
      const int idx = j * 512 + tid;          // e = idx>>7, col = idx&127
      bS[idx] = bias2[((idx >> 7) << 11) + h0 + (idx & 127)];
    }
  }
  asm volatile("s_waitcnt vmcnt(6) lgkmcnt(0)" ::: "memory");
  __builtin_amdgcn_s_barrier();
  __builtin_amdgcn_sched_barrier(0);

  f32x4 sum[4][4], acc[4][4];
#pragma unroll
  for (int m = 0; m < 4; ++m)
#pragma unroll
    for (int n = 0; n < 4; ++n) {
      sum[m][n] = (f32x4){0.f, 0.f, 0.f, 0.f};
      acc[m][n] = (f32x4){0.f, 0.f, 0.f, 0.f};
    }

  int bC = 0, bN = 49152, bS2 = 98304;  // compute / next / stage targets

  for (int g = 0; g < 128; ++g) {
    if (g < 126) STAGE8(bS2, g + 2);

#pragma unroll
    for (int s = 0; s < 2; ++s) {
      bf16x8 aF[4], bF[4];
#pragma unroll
      for (int m = 0; m < 4; ++m)
        aF[m] = *(const bf16x8*)(smem + bC + aRd[m][s]);
#pragma unroll
      for (int n = 0; n < 4; ++n)
        bF[n] = *(const bf16x8*)(smem + bC + bRd[n][s]);
      asm volatile("s_waitcnt lgkmcnt(0)" ::: "memory");
      __builtin_amdgcn_sched_barrier(0);
      __builtin_amdgcn_s_setprio(1);
#pragma unroll
      for (int m = 0; m < 4; ++m)
#pragma unroll
        for (int n = 0; n < 4; ++n)
          acc[m][n] = __builtin_amdgcn_mfma_f32_16x16x32_bf16(
              aF[m], bF[n], acc[m][n], 0, 0, 0);
      __builtin_amdgcn_s_setprio(0);
    }

    if ((g & 7) == 7) {  // expert merge (uniform branch, register-only)
      const float* bv =
          (const float*)(smem + 147456) + ((g >> 3) << 7) + wn + lm;
#pragma unroll
      for (int n = 0; n < 4; ++n) {
        const float bvn = bv[n * 16];
#pragma unroll
        for (int m = 0; m < 4; ++m)
#pragma unroll
          for (int u = 0; u < 4; ++u) {
            sum[m][n][u] += fmaxf(acc[m][n][u] + bvn, 0.f);
            acc[m][n][u] = 0.f;
          }
      }
    }

    // counted drain: leaves stage(g+2)'s 6 loads in flight across barrier.
    if (g < 126)
      asm volatile("s_waitcnt vmcnt(6)" ::: "memory");
    else
      asm volatile("s_waitcnt vmcnt(0)" ::: "memory");
    __builtin_amdgcn_s_barrier();
    __builtin_amdgcn_sched_barrier(0);

    const int t_ = bC; bC = bN; bN = bS2; bS2 = t_;
  }
#undef STAGE8

  // write: C/D layout col=lane&15, row=(lane>>4)*4+reg  [verified m89/m91]
#pragma unroll
  for (int m = 0; m < 4; ++m)
#pragma unroll
    for (int n = 0; n < 4; ++n)
#pragma unroll
      for (int u = 0; u < 4; ++u)
        out[(size_t)(m0 + wm + m * 16 + q * 4 + u) * H_DIM +
            h0 + wn + n * 16 + lm] = sum[m][n][u];
}

// ---------------------------------------------------------------------------
// Fallback path A: R6-verified GEMM (167 us).
// ---------------------------------------------------------------------------
__global__ __launch_bounds__(256, 4) void moe_gemm(
    const __hip_bfloat16* __restrict__ Xb, const __hip_bfloat16* __restrict__ Wb,
    const float* __restrict__ bias2, float* __restrict__ out) {
  __shared__ __align__(16) __hip_bfloat16 As[2][128 * 32];
  __shared__ __align__(16) __hip_bfloat16 Bs[2][2][64 * 32];
  __shared__ __align__(16) float biasS[E_DIM * 64];

  const int tid = threadIdx.x;
  const int lane = tid & 63;
  const int wave = tid >> 6;
  const int hi = blockIdx.x & 31;
  const int mi = blockIdx.x >> 5;
  const int m0 = mi * 128;
  const int h0 = hi * 64;

  for (int idx = tid; idx < E_DIM * 64; idx += 256) {
    biasS[idx] = bias2[((idx >> 6) << 11) + h0 + (idx & 63)];
  }

  const int wm = (wave & 1) * 64;
  const int wn = (wave >> 1) * 32;
  const int lm = lane & 15;
  const int q = lane >> 4;

  const int r = tid >> 2;
  const int fr = (r >> 1) & 3;
  const int col = (((tid & 3) ^ fr)) << 3;
  const size_t aOff0 = (size_t)(m0 + r) * D_DIM + col;
  const size_t aOff1 = (size_t)(m0 + r + 64) * D_DIM + col;
  const size_t bOff = (size_t)(h0 + r) * D_DIM + col;
  const int ldA0 = tid * 8;
  const int ldA1 = (tid + 256) * 8;
  const int ldB = tid * 8;

  int offA[4], offB[2];
#pragma unroll
  for (int i = 0; i < 4; ++i) {
    const int R = wm + i * 16 + lm;
    offA[i] = R * 32 + ((q ^ ((R >> 1) & 3)) << 3);
  }
#pragma unroll
  for (int j = 0; j < 2; ++j) {
    const int R = wn + j * 16 + lm;
    offB[j] = R * 32 + ((q ^ ((R >> 1) & 3)) << 3);
  }

  f32x4 sum[4][2], acc0[4][2], acc1[4][2];
#pragma unroll
  for (int i = 0; i < 4; ++i)
#pragma unroll
    for (int j = 0; j < 2; ++j) {
      sum[i][j] = (f32x4){0.f, 0.f, 0.f, 0.f};
      acc0[i][j] = (f32x4){0.f, 0.f, 0.f, 0.f};
      acc1[i][j] = (f32x4){0.f, 0.f, 0.f, 0.f};
    }

#define STAGE(buf, tt)                                                      \
  {                                                                         \
    const int kk = ((tt) & 15) << 5;                                        \
    const __hip_bfloat16* Bb = Wb + ((size_t)((tt) >> 4) << 21) + bOff + kk;\
    async_copy16(Xb + aOff0 + kk, &As[buf][ldA0]);                          \
    async_copy16(Xb + aOff1 + kk, &As[buf][ldA1]);                          \
    async_copy16(Bb, &Bs[buf][0][ldB]);                                     \
    async_copy16(Bb + ((size_t)1 << 20), &Bs[buf][1][ldB]);                 \
  }

  STAGE(0, 0);
  __syncthreads();

  for (int t = 0; t < 128; ++t) {
    const int cur = t & 1;
    if (t < 127) STAGE(cur ^ 1, t + 1);

    bf16x8 af[4];
#pragma unroll
    for (int i = 0; i < 4; ++i) af[i] = *(const bf16x8*)&As[cur][offA[i]];

#pragma unroll
    for (int j = 0; j < 2; ++j) {
      const bf16x8 b0 = *(const bf16x8*)&Bs[cur][0][offB[j]];
#pragma unroll
      for (int i = 0; i < 4; ++i)
        acc0[i][j] = __builtin_amdgcn_mfma_f32_16x16x32_bf16(
            af[i], b0, acc0[i][j], 0, 0, 0);
      const bf16x8 b1 = *(const bf16x8*)&Bs[cur][1][offB[j]];
#pragma unroll
      for (int i = 0; i < 4; ++i)
        acc1[i][j] = __builtin_amdgcn_mfma_f32_16x16x32_bf16(
            af[i], b1, acc1[i][j], 0, 0, 0);
    }

    if ((t & 15) == 15) {
      const int pair = t >> 4;
#pragma unroll
      for (int j = 0; j < 2; ++j) {
        const float bv0 = biasS[(2 * pair) * 64 + wn + j * 16 + lm];
        const float bv1 = biasS[(2 * pair + 1) * 64 + wn + j * 16 + lm];
#pragma unroll
        for (int i = 0; i < 4; ++i)
#pragma unroll
          for (int u = 0; u < 4; ++u) {
            sum[i][j][u] += fmaxf(acc0[i][j][u] + bv0, 0.f) +
                            fmaxf(acc1[i][j][u] + bv1, 0.f);
            acc0[i][j][u] = 0.f;
            acc1[i][j][u] = 0.f;
          }
      }
    }

    __syncthreads();
  }
#undef STAGE

  const int rbase = q * 4;
#pragma unroll
  for (int i = 0; i < 4; ++i)
#pragma unroll
    for (int j = 0; j < 2; ++j)
#pragma unroll
      for (int u = 0; u < 4; ++u)
        out[(size_t)(m0 + wm + i * 16 + rbase + u) * H_DIM + h0 + wn + j * 16 + lm] =
            sum[i][j][u];
}

// ---------------------------------------------------------------------------
// Fallback path B (workspace too small): naive fp32.
// ---------------------------------------------------------------------------
__global__ __launch_bounds__(256) void naive_kernel(
    const float* __restrict__ x, const float* __restrict__ c,
    const float* __restrict__ W, const float* __restrict__ bias,
    float* __restrict__ out) {
  const int idx = blockIdx.x * 256 + threadIdx.x;
  const int b = idx >> 11;
  const int h = idx & (H_DIM - 1);
  const float* xr = x + (size_t)b * D_DIM;
  float s = 0.f;
  for (int e = 0; e < E_DIM; ++e) {
    const float* wr = W + ((size_t)e * H_DIM + h) * D_DIM;
    const float* cr = c + (size_t)e * D_DIM;
    float acc = bias[e * H_DIM + h];
    for (int d = 0; d < D_DIM; ++d) acc += (xr[d] - cr[d]) * wr[d];
    s += fmaxf(acc, 0.f);
  }
  out[idx] = s;
}

extern "C" void kernel_launch(void* const* d_in, const int* in_sizes, int n_in,
                              void* d_out, int out_size, void* d_ws, size_t ws_size,
                              hipStream_t stream) {
  const float* x = (const float*)d_in[0];     // [4096, 512]
  const float* c = (const float*)d_in[1];     // [16, 512]
  const float* W = (const float*)d_in[2];     // [16, 2048, 512]
  const float* b = (const float*)d_in[3];     // [16, 2048]
  float* out = (float*)d_out;                 // [4096, 2048]

  const size_t sz_wb = (size_t)E_DIM * H_DIM * D_DIM * 2;  // 32 MB
  const size_t sz_xb = (size_t)B_DIM * D_DIM * 2;          // 4 MB
  const size_t sz_b2 = (size_t)E_DIM * H_DIM * 4;          // 128 KB
  const size_t need = sz_wb + sz_xb + sz_b2;

  if (ws_size >= need) {
    __hip_bfloat16* Wb = (__hip_bfloat16*)((char*)d_ws);
    __hip_bfloat16* Xb = (__hip_bfloat16*)((char*)d_ws + sz_wb);
    float* bias2 = (float*)((char*)d_ws + sz_wb + sz_xb);

    // one-time: verify 152KB-LDS kernel is launchable (>=1 block/CU)
    static int g8_ok = -1;
    if (g8_ok < 0) {
      int nb = 0;
      hipError_t e =
          hipOccupancyMaxActiveBlocksPerMultiprocessor(&nb, moe_gemm8, 512, 0);
      g8_ok = (e == hipSuccess && nb >= 1) ? 1 : 0;
    }

    prep<<<5120, 256, 0, stream>>>(W, c, b, x, Wb, bias2, Xb);
    if (g8_ok) {
      moe_gemm8<<<256, 512, 0, stream>>>(Xb, Wb, bias2, out);
    } else {
      moe_gemm<<<1024, 256, 0, stream>>>(Xb, Wb, bias2, out);
    }
  } else {
    naive_kernel<<<(B_DIM * H_DIM) / 256, 256, 0, stream>>>(x, c, W, b, out);
  }
}